// Round 10
// baseline (265.187 us; speedup 1.0000x reference)
//
#include <hip/hip_runtime.h>
#include <math.h>

#define S_LEN 2048
#define DIM   1024
#define HEADS 16
#define DK    64
#define BATCH 4

typedef __bf16 bf16;
typedef bf16  bf16x8 __attribute__((ext_vector_type(8)));
typedef bf16  bf16x4 __attribute__((ext_vector_type(4)));
typedef float f32x4  __attribute__((ext_vector_type(4)));
typedef unsigned long long u64;

#define QSCALE (0.125f * 1.44269504088896f)   // 1/sqrt(dk) * log2(e)

__device__ __forceinline__ void gload16(const void* g, void* l) {
  __builtin_amdgcn_global_load_lds((const __attribute__((address_space(1))) void*)g,
                                   (__attribute__((address_space(3))) void*)l, 16, 0, 0);
}
__device__ __forceinline__ float exp2fast(float x) {
  float r; asm("v_exp_f32 %0, %1" : "=v"(r) : "v"(x)); return r;
}
__device__ __forceinline__ void barrier_raw() {
  asm volatile("" ::: "memory");
  __builtin_amdgcn_s_barrier();
  asm volatile("" ::: "memory");
}

// ---------------------------------------------------------------------------
// Mask bitpack: 67 MB int32 -> 2 MB u64 bitmask (L2-resident).
// ---------------------------------------------------------------------------
__global__ __launch_bounds__(256)
void pack_mask(const int* __restrict__ mask, u64* __restrict__ bits)
{
  const int w    = blockIdx.x * 4 + (threadIdx.x >> 6);
  const int lane = threadIdx.x & 63;
  const int mv   = mask[(size_t)w * 64 + lane];
  const u64 b    = __ballot(mv != 0);
  if (lane == 0) bits[w] = b;
}

// ---------------------------------------------------------------------------
// f32 -> bf16 conversion, 8 elems/thread. blockIdx.y selects tensor (up to 4).
// ---------------------------------------------------------------------------
__global__ __launch_bounds__(256)
void conv_bf16(const float* __restrict__ i0, const float* __restrict__ i1,
               const float* __restrict__ i2, const float* __restrict__ i3,
               bf16* __restrict__ o0, bf16* __restrict__ o1,
               bf16* __restrict__ o2, bf16* __restrict__ o3)
{
  const int t = blockIdx.y;
  const float* in = (t == 0) ? i0 : (t == 1) ? i1 : (t == 2) ? i2 : i3;
  bf16* out      = (t == 0) ? o0 : (t == 1) ? o1 : (t == 2) ? o2 : o3;
  const size_t idx = ((size_t)blockIdx.x * 256 + threadIdx.x) * 8;
  float4 a = *reinterpret_cast<const float4*>(&in[idx]);
  float4 b = *reinterpret_cast<const float4*>(&in[idx + 4]);
  bf16x8 r;
  r[0] = (bf16)a.x; r[1] = (bf16)a.y; r[2] = (bf16)a.z; r[3] = (bf16)a.w;
  r[4] = (bf16)b.x; r[5] = (bf16)b.y; r[6] = (bf16)b.z; r[7] = (bf16)b.w;
  *reinterpret_cast<bf16x8*>(&out[idx]) = r;
}

// ---------------------------------------------------------------------------
// bf16 NT GEMM: C[M][N] = A[M][K] @ W[N][K]^T + bias[N]
// MODE 0: bf16 out | 1: bf16 out transposed Vt[b][n][s] | 2: f32 out
// MODE 3: bf16 out scaled by QSCALE (Q projection)
// T4 counted-vmcnt: stage t+1 -> vmcnt(8) -> raw barrier; t+1's 8 loads stay
// in flight across the whole compute. Raw s_barrier avoids the compiler's
// vmcnt(0) drain that __syncthreads would force.
// ---------------------------------------------------------------------------
#define GSTAGE(K0, NB) do {                                                    \
    _Pragma("unroll")                                                          \
    for (int j = 0; j < 4; ++j) {                                              \
      const int chunk = j * 256 + tid;                                         \
      const int rr = chunk >> 3;                                               \
      const int cG = ((chunk & 7) << 4) ^ ((rr & 7) << 4);                     \
      gload16(Ab + ((size_t)(m0 + rr) * K + (K0)) * 2 + cG,                    \
              (char*)&As[NB][0][0] + chunk * 16);                              \
      gload16(Wb + ((size_t)(n0 + rr) * K + (K0)) * 2 + cG,                    \
              (char*)&Bs[NB][0][0] + chunk * 16);                              \
    }                                                                          \
  } while (0)

template<int MODE>
__global__ __launch_bounds__(256)
void gemm_bt(const bf16* __restrict__ A, const bf16* __restrict__ W,
             const float* __restrict__ bias, void* __restrict__ Cout,
             int M, int N, int K)
{
  __shared__ __align__(16) bf16 As[2][128][64];
  __shared__ __align__(16) bf16 Bs[2][128][64];
  const int tid  = threadIdx.x;
  const int lane = tid & 63, wid = tid >> 6;
  const int l15  = lane & 15, lg = lane >> 4;
  const int L  = (blockIdx.x & 7) * 64 + (blockIdx.x >> 3);
  const int m0 = (L >> 3) * 128, n0 = (L & 7) * 128;
  const int wm = wid >> 1, wn = wid & 1;
  const char* Ab = (const char*)A;
  const char* Wb = (const char*)W;

  f32x4 acc[4][4] = {};

  GSTAGE(0, 0);

  int cur = 0;
  const int NT = K >> 6;
  for (int t = 0; t < NT; ++t) {
    if (t + 1 < NT) {
      GSTAGE((t + 1) << 6, cur ^ 1);
      asm volatile("s_waitcnt vmcnt(8)" ::: "memory");   // tile t landed; t+1 in flight
    } else {
      asm volatile("s_waitcnt vmcnt(0)" ::: "memory");
    }
    barrier_raw();

    bf16x8 af[4][2], bfr[4][2];
    #pragma unroll
    for (int i = 0; i < 4; ++i) {
      const int ra = wm * 64 + i * 16 + l15;
      const int rb = wn * 64 + i * 16 + l15;
      #pragma unroll
      for (int s = 0; s < 2; ++s) {
        const int co = (s * 64 + lg * 16);
        af[i][s]  = *reinterpret_cast<const bf16x8*>(
            (const char*)&As[cur][0][0] + ra * 128 + (co ^ ((ra & 7) << 4)));
        bfr[i][s] = *reinterpret_cast<const bf16x8*>(
            (const char*)&Bs[cur][0][0] + rb * 128 + (co ^ ((rb & 7) << 4)));
      }
    }
    __builtin_amdgcn_s_setprio(1);
    #pragma unroll
    for (int s = 0; s < 2; ++s)
      #pragma unroll
      for (int mi = 0; mi < 4; ++mi)
        #pragma unroll
        for (int ni = 0; ni < 4; ++ni)
          acc[mi][ni] = __builtin_amdgcn_mfma_f32_16x16x32_bf16(af[mi][s], bfr[ni][s], acc[mi][ni], 0, 0, 0);
    __builtin_amdgcn_s_setprio(0);

    barrier_raw();        // all waves done reading cur before next iter overwrites
    cur ^= 1;
  }

  // epilogue: C row = lg*4 + reg, col = l15 within each 16x16 fragment
  #pragma unroll
  for (int ni = 0; ni < 4; ++ni) {
    const int col = n0 + wn * 64 + ni * 16 + l15;
    const float bi = bias[col];
    #pragma unroll
    for (int mi = 0; mi < 4; ++mi) {
      const int row0 = m0 + wm * 64 + mi * 16 + lg * 4;
      if (MODE == 0) {
        bf16* out = (bf16*)Cout;
        #pragma unroll
        for (int r = 0; r < 4; ++r)
          out[(size_t)(row0 + r) * N + col] = (bf16)(acc[mi][ni][r] + bi);
      } else if (MODE == 1) {
        bf16* out = (bf16*)Cout;
        bf16x4 vv;
        #pragma unroll
        for (int r = 0; r < 4; ++r) vv[r] = (bf16)(acc[mi][ni][r] + bi);
        *reinterpret_cast<bf16x4*>(
            &out[((size_t)(row0 >> 11) * DIM + col) * S_LEN + (row0 & (S_LEN - 1))]) = vv;
      } else if (MODE == 3) {
        bf16* out = (bf16*)Cout;
        #pragma unroll
        for (int r = 0; r < 4; ++r)
          out[(size_t)(row0 + r) * N + col] = (bf16)((acc[mi][ni][r] + bi) * QSCALE);
      } else {
        float* out = (float*)Cout;
        #pragma unroll
        for (int r = 0; r < 4; ++r)
          out[(size_t)(row0 + r) * N + col] = acc[mi][ni][r] + bi;
      }
    }
  }
}

// ---------------------------------------------------------------------------
// Flash attention, static-max softmax, prescaled Q, PIPELINED (T15 variant):
// iter t = [sync] stage K(t+1),V(t) ; QK(t) ; PV(t-1) ; SM(t) ; Pwrite(t).
// PV(t-1) is independent of QK(t)->SM(t), so its MFMAs/vf-reads hide the
// softmax VALU. V is consumed one iter after staging (latency fully covered).
// Mask applied as additive bias (sign-extended bit & f32(-9984)) before exp2.
// ---------------------------------------------------------------------------
#define STAGE_K(KT, NB) do {                                                   \
    const int rr = tid >> 3;                                                   \
    const int cG = ((tid & 7) << 4) ^ ((rr & 7) << 4);                         \
    gload16(KbB + ((size_t)(b * S_LEN + (KT) + rr) * DIM + h * DK) * 2 + cG,   \
            (char*)&Kbuf[NB][0][0] + tid * 16);                                \
  } while (0)
#define STAGE_V(KT, NB) do {                                                   \
    const int rr = tid >> 3;                                                   \
    const int cG = ((tid & 7) << 4) ^ ((rr & 7) << 4);                         \
    gload16(VtB + ((size_t)b * DIM + h * DK + rr) * (S_LEN * 2) + (KT) * 2 + cG, \
            (char*)&Vbuf[NB][0][0] + tid * 16);                                \
  } while (0)

__global__ __launch_bounds__(512, 4)
void attn_fwd(const bf16* __restrict__ Qb, const bf16* __restrict__ Kb,
              const bf16* __restrict__ Vt, const u64* __restrict__ mbits,
              bf16* __restrict__ ctx)
{
  __shared__ __align__(16) bf16 Kbuf[2][64][64];
  __shared__ __align__(16) bf16 Vbuf[2][64][64];
  __shared__ __align__(16) bf16 Plds[8][32][72];

  const int tid  = threadIdx.x;
  const int lane = tid & 63, w = tid >> 6;
  const int l15  = lane & 15, lg = lane >> 4;
  const int L  = (blockIdx.x & 7) * 64 + (blockIdx.x >> 3);
  const int qi = L & 7;
  const int hb = L >> 3;
  const int h  = hb & 15, b = hb >> 4;
  const int qbase = qi * 256 + w * 32;

  const char* KbB = (const char*)Kb;
  const char* VtB = (const char*)Vt;

  // Q fragments (B-operand), rows q = qbase + qg*16 + l15  (Q prescaled)
  bf16x8 qf[2][2];
  #pragma unroll
  for (int qg = 0; qg < 2; ++qg) {
    const size_t qrow = (size_t)b * S_LEN + qbase + qg * 16 + l15;
    #pragma unroll
    for (int s = 0; s < 2; ++s)
      qf[qg][s] = *reinterpret_cast<const bf16x8*>(&Qb[qrow * DIM + h * DK + s * 32 + lg * 8]);
  }

  bf16x8 onesf;
  #pragma unroll
  for (int j = 0; j < 8; ++j) onesf[j] = (bf16)1.0f;

  f32x4 o[2][4] = {};
  f32x4 o_l[2] = {};
  const u64* mrow[2];
  mrow[0] = mbits + ((size_t)b * S_LEN + qbase + l15) * (S_LEN / 64);
  mrow[1] = mrow[0] + (size_t)16 * (S_LEN / 64);

  // prologue: K(0) -> kb0, mask(0)
  STAGE_K(0, 0);
  u64 mbc[2] = { mrow[0][0], mrow[1][0] };

  const int NT = S_LEN / 64;   // 32
  for (int t = 0; t < NT; ++t) {
    asm volatile("s_waitcnt vmcnt(0)" ::: "memory");  // K(t), V(t-1) landed (mine)
    __syncthreads();                                  // ... and everyone's

    // issue next-tile loads (stay in flight across this iter)
    u64 mbn[2] = {0, 0};
    if (t + 1 < NT) {
      mbn[0] = mrow[0][t + 1];
      mbn[1] = mrow[1][t + 1];
      STAGE_K((t + 1) * 64, (t + 1) & 1);
    }
    STAGE_V(t * 64, t & 1);

    // --- QK(t): sc[qg][nf][r] = S[k][q] from Kbuf[t&1]
    f32x4 sc[2][4] = {};
    __builtin_amdgcn_s_setprio(1);
    #pragma unroll
    for (int s = 0; s < 2; ++s)
      #pragma unroll
      for (int nf = 0; nf < 4; ++nf) {
        const int row = nf * 16 + l15;
        bf16x8 kf = *reinterpret_cast<const bf16x8*>(
            (const char*)&Kbuf[t & 1][row][0] + (((s * 64 + lg * 16)) ^ ((row & 7) << 4)));
        sc[0][nf] = __builtin_amdgcn_mfma_f32_16x16x32_bf16(kf, qf[0][s], sc[0][nf], 0, 0, 0);
        sc[1][nf] = __builtin_amdgcn_mfma_f32_16x16x32_bf16(kf, qf[1][s], sc[1][nf], 0, 0, 0);
      }

    // --- PV(t-1): independent of QK/SM above -> scheduler overlaps them
    if (t > 0) {
      #pragma unroll
      for (int s = 0; s < 2; ++s) {
        bf16x8 pf0 = *reinterpret_cast<const bf16x8*>(&Plds[w][l15][s * 32 + lg * 8]);
        bf16x8 pf1 = *reinterpret_cast<const bf16x8*>(&Plds[w][16 + l15][s * 32 + lg * 8]);
        #pragma unroll
        for (int nf = 0; nf < 4; ++nf) {
          const int row = nf * 16 + l15;
          bf16x8 vf = *reinterpret_cast<const bf16x8*>(
              (const char*)&Vbuf[(t - 1) & 1][row][0] + (((s * 64 + lg * 16)) ^ ((row & 7) << 4)));
          o[0][nf] = __builtin_amdgcn_mfma_f32_16x16x32_bf16(pf0, vf, o[0][nf], 0, 0, 0);
          o[1][nf] = __builtin_amdgcn_mfma_f32_16x16x32_bf16(pf1, vf, o[1][nf], 0, 0, 0);
        }
        o_l[0] = __builtin_amdgcn_mfma_f32_16x16x32_bf16(pf0, onesf, o_l[0], 0, 0, 0);
        o_l[1] = __builtin_amdgcn_mfma_f32_16x16x32_bf16(pf1, onesf, o_l[1], 0, 0, 0);
      }
    }
    __builtin_amdgcn_s_setprio(0);

    // --- SM(t): p = exp2(sc + mask_bias); masked bias = -9984 -> p == 0
    #pragma unroll
    for (int qg = 0; qg < 2; ++qg) {
      #pragma unroll
      for (int nf = 0; nf < 4; ++nf) {
        const unsigned inv = ~(unsigned)(mbc[qg] >> (nf * 16 + lg * 4));
        bf16x4 pv;
        #pragma unroll
        for (int r = 0; r < 4; ++r) {
          const int sext = ((int)(inv << (31 - r))) >> 31;      // bit -> 0 / -1
          const float bias = __int_as_float(sext & 0xC61C4000); // 0 / -9984.0f
          pv[r] = (bf16)exp2fast(sc[qg][nf][r] + bias);
        }
        *reinterpret_cast<bf16x4*>(&Plds[w][qg * 16 + l15][nf * 16 + lg * 4]) = pv;
      }
    }

    mbc[0] = mbn[0]; mbc[1] = mbn[1];
  }

  // --- final PV(NT-1)
  asm volatile("s_waitcnt vmcnt(0)" ::: "memory");
  __syncthreads();
  __builtin_amdgcn_s_setprio(1);
  #pragma unroll
  for (int s = 0; s < 2; ++s) {
    bf16x8 pf0 = *reinterpret_cast<const bf16x8*>(&Plds[w][l15][s * 32 + lg * 8]);
    bf16x8 pf1 = *reinterpret_cast<const bf16x8*>(&Plds[w][16 + l15][s * 32 + lg * 8]);
    #pragma unroll
    for (int nf = 0; nf < 4; ++nf) {
      const int row = nf * 16 + l15;
      bf16x8 vf = *reinterpret_cast<const bf16x8*>(
          (const char*)&Vbuf[(NT - 1) & 1][row][0] + (((s * 64 + lg * 16)) ^ ((row & 7) << 4)));
      o[0][nf] = __builtin_amdgcn_mfma_f32_16x16x32_bf16(pf0, vf, o[0][nf], 0, 0, 0);
      o[1][nf] = __builtin_amdgcn_mfma_f32_16x16x32_bf16(pf1, vf, o[1][nf], 0, 0, 0);
    }
    o_l[0] = __builtin_amdgcn_mfma_f32_16x16x32_bf16(pf0, onesf, o_l[0], 0, 0, 0);
    o_l[1] = __builtin_amdgcn_mfma_f32_16x16x32_bf16(pf1, onesf, o_l[1], 0, 0, 0);
  }
  __builtin_amdgcn_s_setprio(0);

  // --- epilogue: o_l[qg][r] is l[q] in o's row layout -> no shuffles
  #pragma unroll
  for (int qg = 0; qg < 2; ++qg) {
    float lf[4];
    #pragma unroll
    for (int r = 0; r < 4; ++r) lf[r] = 1.0f / o_l[qg][r];
    #pragma unroll
    for (int nf = 0; nf < 4; ++nf)
      #pragma unroll
      for (int r = 0; r < 4; ++r) {
        const int q = qbase + qg * 16 + lg * 4 + r;
        ctx[((size_t)b * S_LEN + q) * DIM + h * DK + nf * 16 + l15] = (bf16)(o[qg][nf][r] * lf[r]);
      }
  }
}

// ---------------------------------------------------------------------------
extern "C" void kernel_launch(void* const* d_in, const int* in_sizes, int n_in,
                              void* d_out, int out_size, void* d_ws, size_t ws_size,
                              hipStream_t stream)
{
  const float* q    = (const float*)d_in[0];
  const float* k    = (const float*)d_in[1];
  const float* v    = (const float*)d_in[2];
  const int*   mask = (const int*)  d_in[3];
  const float* Wq   = (const float*)d_in[4];
  const float* bq   = (const float*)d_in[5];
  const float* Wk   = (const float*)d_in[6];
  const float* bk   = (const float*)d_in[7];
  const float* Wv   = (const float*)d_in[8];
  const float* bv   = (const float*)d_in[9];
  const float* Wo   = (const float*)d_in[10];
  const float* bo   = (const float*)d_in[11];
  float* out = (float*)d_out;

  const size_t NE = (size_t)BATCH * S_LEN * DIM;  // 8.39M elements
  const size_t NW = (size_t)DIM * DIM;            // 1.05M elements
  bf16* qB  = (bf16*)d_ws;                        // bf16 copies of inputs
  bf16* kB  = qB + NE;
  bf16* vB  = kB + NE;
  bf16* Qb  = vB + NE;                            // projected Q,K,V
  bf16* Kb  = Qb + NE;
  bf16* Vt  = Kb + NE;
  bf16* WqB = Vt + NE;                            // bf16 weights
  bf16* WkB = WqB + NW;
  bf16* WvB = WkB + NW;
  bf16* WoB = WvB + NW;
  u64*  bits = (u64*)(WoB + NW);                  // 2 MB
  bf16* ctx = qB;                                 // reuse: qB dead after GEMM1

  const int M = BATCH * S_LEN;  // 8192

  pack_mask<<<(BATCH * S_LEN * (S_LEN / 64)) / 4, 256, 0, stream>>>(mask, bits);
  conv_bf16<<<dim3(NE / 2048, 3), 256, 0, stream>>>(q, k, v, v, qB, kB, vB, vB);
  conv_bf16<<<dim3(NW / 2048, 4), 256, 0, stream>>>(Wq, Wk, Wv, Wo, WqB, WkB, WvB, WoB);

  gemm_bt<3><<<512, 256, 0, stream>>>(qB, WqB, bq, Qb, M, DIM, DIM);   // Q prescaled
  gemm_bt<0><<<512, 256, 0, stream>>>(kB, WkB, bk, Kb, M, DIM, DIM);
  gemm_bt<1><<<512, 256, 0, stream>>>(vB, WvB, bv, Vt, M, DIM, DIM);

  attn_fwd<<<512, 512, 0, stream>>>(Qb, Kb, Vt, bits, ctx);

  gemm_bt<2><<<512, 256, 0, stream>>>(ctx, WoB, bo, out, M, DIM, DIM);
}

// Round 11
// 246.332 us; speedup vs baseline: 1.0765x; 1.0765x over previous
//
#include <hip/hip_runtime.h>
#include <math.h>

#define S_LEN 2048
#define DIM   1024
#define HEADS 16
#define DK    64
#define BATCH 4

typedef __bf16 bf16;
typedef bf16  bf16x8 __attribute__((ext_vector_type(8)));
typedef bf16  bf16x4 __attribute__((ext_vector_type(4)));
typedef float f32x4  __attribute__((ext_vector_type(4)));
typedef unsigned long long u64;

#define QSCALE (0.125f * 1.44269504088896f)   // 1/sqrt(dk) * log2(e)

__device__ __forceinline__ void gload16(const void* g, void* l) {
  __builtin_amdgcn_global_load_lds((const __attribute__((address_space(1))) void*)g,
                                   (__attribute__((address_space(3))) void*)l, 16, 0, 0);
}
__device__ __forceinline__ float exp2fast(float x) {
  float r; asm("v_exp_f32 %0, %1" : "=v"(r) : "v"(x)); return r;
}
__device__ __forceinline__ unsigned cvt_pk_bf16(float a, float b) {
  unsigned r; asm("v_cvt_pk_bf16_f32 %0, %1, %2" : "=v"(r) : "v"(a), "v"(b)); return r;
}

// ---------------------------------------------------------------------------
// Mask bitpack: 67 MB int32 -> 2 MB u64 bitmask (L2-resident).
// ---------------------------------------------------------------------------
__global__ __launch_bounds__(256)
void pack_mask(const int* __restrict__ mask, u64* __restrict__ bits)
{
  const int w    = blockIdx.x * 4 + (threadIdx.x >> 6);
  const int lane = threadIdx.x & 63;
  const int mv   = mask[(size_t)w * 64 + lane];
  const u64 b    = __ballot(mv != 0);
  if (lane == 0) bits[w] = b;
}

// ---------------------------------------------------------------------------
// f32 -> bf16 conversion, 8 elems/thread. blockIdx.y selects tensor (up to 4).
// ---------------------------------------------------------------------------
__global__ __launch_bounds__(256)
void conv_bf16(const float* __restrict__ i0, const float* __restrict__ i1,
               const float* __restrict__ i2, const float* __restrict__ i3,
               bf16* __restrict__ o0, bf16* __restrict__ o1,
               bf16* __restrict__ o2, bf16* __restrict__ o3)
{
  const int t = blockIdx.y;
  const float* in = (t == 0) ? i0 : (t == 1) ? i1 : (t == 2) ? i2 : i3;
  bf16* out      = (t == 0) ? o0 : (t == 1) ? o1 : (t == 2) ? o2 : o3;
  const size_t idx = ((size_t)blockIdx.x * 256 + threadIdx.x) * 8;
  float4 a = *reinterpret_cast<const float4*>(&in[idx]);
  float4 b = *reinterpret_cast<const float4*>(&in[idx + 4]);
  bf16x8 r;
  r[0] = (bf16)a.x; r[1] = (bf16)a.y; r[2] = (bf16)a.z; r[3] = (bf16)a.w;
  r[4] = (bf16)b.x; r[5] = (bf16)b.y; r[6] = (bf16)b.z; r[7] = (bf16)b.w;
  *reinterpret_cast<bf16x8*>(&out[idx]) = r;
}

// ---------------------------------------------------------------------------
// bf16 NT GEMM: C[M][N] = A[M][K] @ W[N][K]^T + bias[N]
// MODE 0: bf16 out | 1: bf16 out transposed + k-PERMUTED Vt[b][n][perm(seq)]
//   (perm within each 64-tile: p = 32*(t6>>5) + 8*((t6>>2)&3) + 4*((t6>>4)&1)
//    + (t6&3) -- matches the register-direct P fragment order in attn PV)
// MODE 2: f32 out | MODE 3: bf16 out scaled by QSCALE (Q projection)
// Round-8 structure (vmcnt(0)+syncthreads; counted-vmcnt T4 reverted: it
// regressed on this 2-phase 128^2 structure, consistent with the regime gate).
// ---------------------------------------------------------------------------
#define GSTAGE(K0, NB) do {                                                    \
    _Pragma("unroll")                                                          \
    for (int j = 0; j < 4; ++j) {                                              \
      const int chunk = j * 256 + tid;                                         \
      const int rr = chunk >> 3;                                               \
      const int cG = ((chunk & 7) << 4) ^ ((rr & 7) << 4);                     \
      gload16(Ab + ((size_t)(m0 + rr) * K + (K0)) * 2 + cG,                    \
              (char*)&As[NB][0][0] + chunk * 16);                              \
      gload16(Wb + ((size_t)(n0 + rr) * K + (K0)) * 2 + cG,                    \
              (char*)&Bs[NB][0][0] + chunk * 16);                              \
    }                                                                          \
  } while (0)

template<int MODE>
__global__ __launch_bounds__(256)
void gemm_bt(const bf16* __restrict__ A, const bf16* __restrict__ W,
             const float* __restrict__ bias, void* __restrict__ Cout,
             int M, int N, int K)
{
  __shared__ __align__(16) bf16 As[2][128][64];
  __shared__ __align__(16) bf16 Bs[2][128][64];
  const int tid  = threadIdx.x;
  const int lane = tid & 63, wid = tid >> 6;
  const int l15  = lane & 15, lg = lane >> 4;
  const int L  = (blockIdx.x & 7) * 64 + (blockIdx.x >> 3);
  const int m0 = (L >> 3) * 128, n0 = (L & 7) * 128;
  const int wm = wid >> 1, wn = wid & 1;
  const char* Ab = (const char*)A;
  const char* Wb = (const char*)W;

  f32x4 acc[4][4] = {};

  GSTAGE(0, 0);
  asm volatile("s_waitcnt vmcnt(0)" ::: "memory");
  __syncthreads();

  int cur = 0;
  const int NT = K >> 6;
  for (int t = 0; t < NT; ++t) {
    if (t + 1 < NT) GSTAGE((t + 1) << 6, cur ^ 1);

    bf16x8 af[4][2], bfr[4][2];
    #pragma unroll
    for (int i = 0; i < 4; ++i) {
      const int ra = wm * 64 + i * 16 + l15;
      const int rb = wn * 64 + i * 16 + l15;
      #pragma unroll
      for (int s = 0; s < 2; ++s) {
        const int co = (s * 64 + lg * 16);
        af[i][s]  = *reinterpret_cast<const bf16x8*>(
            (const char*)&As[cur][0][0] + ra * 128 + (co ^ ((ra & 7) << 4)));
        bfr[i][s] = *reinterpret_cast<const bf16x8*>(
            (const char*)&Bs[cur][0][0] + rb * 128 + (co ^ ((rb & 7) << 4)));
      }
    }
    __builtin_amdgcn_s_setprio(1);
    #pragma unroll
    for (int s = 0; s < 2; ++s)
      #pragma unroll
      for (int mi = 0; mi < 4; ++mi)
        #pragma unroll
        for (int ni = 0; ni < 4; ++ni)
          acc[mi][ni] = __builtin_amdgcn_mfma_f32_16x16x32_bf16(af[mi][s], bfr[ni][s], acc[mi][ni], 0, 0, 0);
    __builtin_amdgcn_s_setprio(0);

    asm volatile("s_waitcnt vmcnt(0)" ::: "memory");
    __syncthreads();
    cur ^= 1;
  }

  // epilogue: C row = lg*4 + reg, col = l15 within each 16x16 fragment
  #pragma unroll
  for (int ni = 0; ni < 4; ++ni) {
    const int col = n0 + wn * 64 + ni * 16 + l15;
    const float bi = bias[col];
    #pragma unroll
    for (int mi = 0; mi < 4; ++mi) {
      const int row0 = m0 + wm * 64 + mi * 16 + lg * 4;
      if (MODE == 0) {
        bf16* out = (bf16*)Cout;
        #pragma unroll
        for (int r = 0; r < 4; ++r)
          out[(size_t)(row0 + r) * N + col] = (bf16)(acc[mi][ni][r] + bi);
      } else if (MODE == 1) {
        bf16* out = (bf16*)Cout;
        bf16x4 vv;
        #pragma unroll
        for (int r = 0; r < 4; ++r) vv[r] = (bf16)(acc[mi][ni][r] + bi);
        const int seq = row0 & (S_LEN - 1);
        const int t6  = seq & 63;
        const int p0  = (seq & ~63) + ((t6 >> 5) << 5) + (((t6 >> 2) & 3) << 3)
                      + (((t6 >> 4) & 1) << 2);
        *reinterpret_cast<bf16x4*>(
            &out[((size_t)(row0 >> 11) * DIM + col) * S_LEN + p0]) = vv;
      } else if (MODE == 3) {
        bf16* out = (bf16*)Cout;
        #pragma unroll
        for (int r = 0; r < 4; ++r)
          out[(size_t)(row0 + r) * N + col] = (bf16)((acc[mi][ni][r] + bi) * QSCALE);
      } else {
        float* out = (float*)Cout;
        #pragma unroll
        for (int r = 0; r < 4; ++r)
          out[(size_t)(row0 + r) * N + col] = acc[mi][ni][r] + bi;
      }
    }
  }
}

// ---------------------------------------------------------------------------
// Flash attention, static-max softmax, prescaled Q, P ENTIRELY IN REGISTERS.
// Swapped QK^T leaves P[k=nf*16+lg*4+r][q=l15] per lane; cvt_pk packs pairs
// into u32 w[nf][rr]. The PV A-fragment {w[2s][0],w[2s][1],w[2s+1][0],
// w[2s+1][1]} has k-order pi(s,lg,j) = 32s + (j>=4)*16 + lg*4 + (j&3); V is
// stored with the SAME permutation (MODE 1 GEMM), so mfma sums match without
// any cross-lane traffic or P-LDS roundtrip. LDS = K/V dbuf only (33 KB).
// ---------------------------------------------------------------------------
#define STAGE(KT, NB) do {                                                     \
    const int rr = tid >> 3;                                                   \
    const int cG = ((tid & 7) << 4) ^ ((rr & 7) << 4);                         \
    gload16(KbB + ((size_t)(b * S_LEN + (KT) + rr) * DIM + h * DK) * 2 + cG,   \
            (char*)&Kbuf[NB][0][0] + tid * 16);                                \
    gload16(VtB + ((size_t)b * DIM + h * DK + rr) * (S_LEN * 2) + (KT) * 2 + cG, \
            (char*)&Vbuf[NB][0][0] + tid * 16);                                \
  } while (0)

__global__ __launch_bounds__(512, 4)
void attn_fwd(const bf16* __restrict__ Qb, const bf16* __restrict__ Kb,
              const bf16* __restrict__ Vt, const u64* __restrict__ mbits,
              bf16* __restrict__ ctx)
{
  __shared__ __align__(16) bf16 Kbuf[2][64][64];
  __shared__ __align__(16) bf16 Vbuf[2][64][64];

  const int tid  = threadIdx.x;
  const int lane = tid & 63;
  const int l15  = lane & 15, lg = lane >> 4;
  const int L  = (blockIdx.x & 7) * 64 + (blockIdx.x >> 3);
  const int qi = L & 7;
  const int hb = L >> 3;
  const int h  = hb & 15, b = hb >> 4;
  const int w  = tid >> 6;
  const int qbase = qi * 256 + w * 32;

  const char* KbB = (const char*)Kb;
  const char* VtB = (const char*)Vt;

  // Q fragments (B-operand), rows q = qbase + qg*16 + l15  (Q prescaled)
  bf16x8 qf[2][2];
  #pragma unroll
  for (int qg = 0; qg < 2; ++qg) {
    const size_t qrow = (size_t)b * S_LEN + qbase + qg * 16 + l15;
    #pragma unroll
    for (int s = 0; s < 2; ++s)
      qf[qg][s] = *reinterpret_cast<const bf16x8*>(&Qb[qrow * DIM + h * DK + s * 32 + lg * 8]);
  }

  bf16x8 onesf;
  #pragma unroll
  for (int j = 0; j < 8; ++j) onesf[j] = (bf16)1.0f;

  typedef union { unsigned u[4]; bf16x8 v; } pfu;

  f32x4 o[2][4] = {};
  f32x4 o_l[2] = {};
  const u64* mrow[2];
  mrow[0] = mbits + ((size_t)b * S_LEN + qbase + l15) * (S_LEN / 64);
  mrow[1] = mrow[0] + (size_t)16 * (S_LEN / 64);

  STAGE(0, 0);
  u64 mbc[2] = { mrow[0][0], mrow[1][0] };

  const int NT = S_LEN / 64;   // 32
  for (int t = 0; t < NT; ++t) {
    asm volatile("s_waitcnt vmcnt(0)" ::: "memory");   // tile t landed
    __syncthreads();

    u64 mbn[2] = {0, 0};
    if (t + 1 < NT) {
      mbn[0] = mrow[0][t + 1];
      mbn[1] = mrow[1][t + 1];
      STAGE((t + 1) * 64, (t + 1) & 1);                // in flight across iter
    }

    // --- QK^T: sc[qg][nf][r] = S[k = kt+nf*16+lg*4+r][q = qbase+qg*16+l15]
    f32x4 sc[2][4] = {};
    __builtin_amdgcn_s_setprio(1);
    #pragma unroll
    for (int s = 0; s < 2; ++s)
      #pragma unroll
      for (int nf = 0; nf < 4; ++nf) {
        const int row = nf * 16 + l15;
        bf16x8 kf = *reinterpret_cast<const bf16x8*>(
            (const char*)&Kbuf[t & 1][row][0] + (((s * 64 + lg * 16)) ^ ((row & 7) << 4)));
        sc[0][nf] = __builtin_amdgcn_mfma_f32_16x16x32_bf16(kf, qf[0][s], sc[0][nf], 0, 0, 0);
        sc[1][nf] = __builtin_amdgcn_mfma_f32_16x16x32_bf16(kf, qf[1][s], sc[1][nf], 0, 0, 0);
      }
    __builtin_amdgcn_s_setprio(0);

    // --- softmax: p = exp2(sc + mask_bias); pack to bf16 pairs in-register
    unsigned wreg[2][4][2];
    #pragma unroll
    for (int qg = 0; qg < 2; ++qg) {
      #pragma unroll
      for (int nf = 0; nf < 4; ++nf) {
        const unsigned inv = ~(unsigned)(mbc[qg] >> (nf * 16 + lg * 4));
        float e[4];
        #pragma unroll
        for (int r = 0; r < 4; ++r) {
          const int sext = ((int)(inv << (31 - r))) >> 31;      // bit -> 0 / -1
          const float bias = __int_as_float(sext & 0xC61C4000); // 0 / -9984.0f
          e[r] = exp2fast(sc[qg][nf][r] + bias);
        }
        wreg[qg][nf][0] = cvt_pk_bf16(e[0], e[1]);
        wreg[qg][nf][1] = cvt_pk_bf16(e[2], e[3]);
      }
    }

    // --- PV: A = P from registers (k-order pi), B = permuted V tile
    __builtin_amdgcn_s_setprio(1);
    #pragma unroll
    for (int s = 0; s < 2; ++s) {
      pfu P0, P1;
      P0.u[0] = wreg[0][2*s][0];   P0.u[1] = wreg[0][2*s][1];
      P0.u[2] = wreg[0][2*s+1][0]; P0.u[3] = wreg[0][2*s+1][1];
      P1.u[0] = wreg[1][2*s][0];   P1.u[1] = wreg[1][2*s][1];
      P1.u[2] = wreg[1][2*s+1][0]; P1.u[3] = wreg[1][2*s+1][1];
      #pragma unroll
      for (int nf = 0; nf < 4; ++nf) {
        const int row = nf * 16 + l15;
        bf16x8 vf = *reinterpret_cast<const bf16x8*>(
            (const char*)&Vbuf[t & 1][row][0] + (((s * 64 + lg * 16)) ^ ((row & 7) << 4)));
        o[0][nf] = __builtin_amdgcn_mfma_f32_16x16x32_bf16(P0.v, vf, o[0][nf], 0, 0, 0);
        o[1][nf] = __builtin_amdgcn_mfma_f32_16x16x32_bf16(P1.v, vf, o[1][nf], 0, 0, 0);
      }
      o_l[0] = __builtin_amdgcn_mfma_f32_16x16x32_bf16(P0.v, onesf, o_l[0], 0, 0, 0);
      o_l[1] = __builtin_amdgcn_mfma_f32_16x16x32_bf16(P1.v, onesf, o_l[1], 0, 0, 0);
    }
    __builtin_amdgcn_s_setprio(0);

    mbc[0] = mbn[0]; mbc[1] = mbn[1];
  }

  // --- epilogue: o_l[qg][r] is l[q] in o's row layout -> no shuffles
  #pragma unroll
  for (int qg = 0; qg < 2; ++qg) {
    float lf[4];
    #pragma unroll
    for (int r = 0; r < 4; ++r) lf[r] = 1.0f / o_l[qg][r];
    #pragma unroll
    for (int nf = 0; nf < 4; ++nf)
      #pragma unroll
      for (int r = 0; r < 4; ++r) {
        const int q = qbase + qg * 16 + lg * 4 + r;
        ctx[((size_t)b * S_LEN + q) * DIM + h * DK + nf * 16 + l15] = (bf16)(o[qg][nf][r] * lf[r]);
      }
  }
}

// ---------------------------------------------------------------------------
extern "C" void kernel_launch(void* const* d_in, const int* in_sizes, int n_in,
                              void* d_out, int out_size, void* d_ws, size_t ws_size,
                              hipStream_t stream)
{
  const float* q    = (const float*)d_in[0];
  const float* k    = (const float*)d_in[1];
  const float* v    = (const float*)d_in[2];
  const int*   mask = (const int*)  d_in[3];
  const float* Wq   = (const float*)d_in[4];
  const float* bq   = (const float*)d_in[5];
  const float* Wk   = (const float*)d_in[6];
  const float* bk   = (const float*)d_in[7];
  const float* Wv   = (const float*)d_in[8];
  const float* bv   = (const float*)d_in[9];
  const float* Wo   = (const float*)d_in[10];
  const float* bo   = (const float*)d_in[11];
  float* out = (float*)d_out;

  const size_t NE = (size_t)BATCH * S_LEN * DIM;  // 8.39M elements
  const size_t NW = (size_t)DIM * DIM;            // 1.05M elements
  bf16* qB  = (bf16*)d_ws;                        // bf16 copies of inputs
  bf16* kB  = qB + NE;
  bf16* vB  = kB + NE;
  bf16* Qb  = vB + NE;                            // projected Q,K,V
  bf16* Kb  = Qb + NE;
  bf16* Vt  = Kb + NE;
  bf16* WqB = Vt + NE;                            // bf16 weights
  bf16* WkB = WqB + NW;
  bf16* WvB = WkB + NW;
  bf16* WoB = WvB + NW;
  u64*  bits = (u64*)(WoB + NW);                  // 2 MB
  bf16* ctx = qB;                                 // reuse: qB dead after GEMM1

  const int M = BATCH * S_LEN;  // 8192

  pack_mask<<<(BATCH * S_LEN * (S_LEN / 64)) / 4, 256, 0, stream>>>(mask, bits);
  conv_bf16<<<dim3(NE / 2048, 3), 256, 0, stream>>>(q, k, v, v, qB, kB, vB, vB);
  conv_bf16<<<dim3(NW / 2048, 4), 256, 0, stream>>>(Wq, Wk, Wv, Wo, WqB, WkB, WvB, WoB);

  gemm_bt<3><<<512, 256, 0, stream>>>(qB, WqB, bq, Qb, M, DIM, DIM);   // Q prescaled
  gemm_bt<0><<<512, 256, 0, stream>>>(kB, WkB, bk, Kb, M, DIM, DIM);
  gemm_bt<1><<<512, 256, 0, stream>>>(vB, WvB, bv, Vt, M, DIM, DIM);   // V k-permuted

  attn_fwd<<<512, 512, 0, stream>>>(Qb, Kb, Vt, bits, ctx);

  gemm_bt<2><<<512, 256, 0, stream>>>(ctx, WoB, bo, out, M, DIM, DIM);
}

// Round 12
// 233.714 us; speedup vs baseline: 1.1347x; 1.0540x over previous
//
#include <hip/hip_runtime.h>
#include <math.h>

#define S_LEN 2048
#define DIM   1024
#define HEADS 16
#define DK    64
#define BATCH 4

typedef __bf16 bf16;
typedef bf16  bf16x8 __attribute__((ext_vector_type(8)));
typedef bf16  bf16x4 __attribute__((ext_vector_type(4)));
typedef float f32x4  __attribute__((ext_vector_type(4)));
typedef unsigned long long u64;

#define QSCALE (0.125f * 1.44269504088896f)   // 1/sqrt(dk) * log2(e)

__device__ __forceinline__ void gload16(const void* g, void* l) {
  __builtin_amdgcn_global_load_lds((const __attribute__((address_space(1))) void*)g,
                                   (__attribute__((address_space(3))) void*)l, 16, 0, 0);
}
__device__ __forceinline__ float exp2fast(float x) {
  float r; asm("v_exp_f32 %0, %1" : "=v"(r) : "v"(x)); return r;
}
__device__ __forceinline__ unsigned cvt_pk_bf16(float a, float b) {
  unsigned r; asm("v_cvt_pk_bf16_f32 %0, %1, %2" : "=v"(r) : "v"(a), "v"(b)); return r;
}

// ---------------------------------------------------------------------------
// Mask bitpack: 67 MB int32 -> 2 MB u64 bitmask (L2-resident).
// ---------------------------------------------------------------------------
__global__ __launch_bounds__(256)
void pack_mask(const int* __restrict__ mask, u64* __restrict__ bits)
{
  const int w    = blockIdx.x * 4 + (threadIdx.x >> 6);
  const int lane = threadIdx.x & 63;
  const int mv   = mask[(size_t)w * 64 + lane];
  const u64 b    = __ballot(mv != 0);
  if (lane == 0) bits[w] = b;
}

// ---------------------------------------------------------------------------
// f32 -> bf16 conversion, 8 elems/thread. blockIdx.y selects tensor (up to 4).
// ---------------------------------------------------------------------------
__global__ __launch_bounds__(256)
void conv_bf16(const float* __restrict__ i0, const float* __restrict__ i1,
               const float* __restrict__ i2, const float* __restrict__ i3,
               bf16* __restrict__ o0, bf16* __restrict__ o1,
               bf16* __restrict__ o2, bf16* __restrict__ o3)
{
  const int t = blockIdx.y;
  const float* in = (t == 0) ? i0 : (t == 1) ? i1 : (t == 2) ? i2 : i3;
  bf16* out      = (t == 0) ? o0 : (t == 1) ? o1 : (t == 2) ? o2 : o3;
  const size_t idx = ((size_t)blockIdx.x * 256 + threadIdx.x) * 8;
  float4 a = *reinterpret_cast<const float4*>(&in[idx]);
  float4 b = *reinterpret_cast<const float4*>(&in[idx + 4]);
  bf16x8 r;
  r[0] = (bf16)a.x; r[1] = (bf16)a.y; r[2] = (bf16)a.z; r[3] = (bf16)a.w;
  r[4] = (bf16)b.x; r[5] = (bf16)b.y; r[6] = (bf16)b.z; r[7] = (bf16)b.w;
  *reinterpret_cast<bf16x8*>(&out[idx]) = r;
}

// ---------------------------------------------------------------------------
// bf16 NT GEMM: C[M][N] = A[M][K] @ W[N][K]^T + bias[N]
// MODE 0: bf16 out | 1: bf16 out transposed + k-PERMUTED Vt[b][n][perm(seq)]
// MODE 2: f32 out | MODE 3: bf16 out scaled by QSCALE (Q projection)
// (unchanged from round 11)
// ---------------------------------------------------------------------------
#define GSTAGE(K0, NB) do {                                                    \
    _Pragma("unroll")                                                          \
    for (int j = 0; j < 4; ++j) {                                              \
      const int chunk = j * 256 + tid;                                         \
      const int rr = chunk >> 3;                                               \
      const int cG = ((chunk & 7) << 4) ^ ((rr & 7) << 4);                     \
      gload16(Ab + ((size_t)(m0 + rr) * K + (K0)) * 2 + cG,                    \
              (char*)&As[NB][0][0] + chunk * 16);                              \
      gload16(Wb + ((size_t)(n0 + rr) * K + (K0)) * 2 + cG,                    \
              (char*)&Bs[NB][0][0] + chunk * 16);                              \
    }                                                                          \
  } while (0)

template<int MODE>
__global__ __launch_bounds__(256)
void gemm_bt(const bf16* __restrict__ A, const bf16* __restrict__ W,
             const float* __restrict__ bias, void* __restrict__ Cout,
             int M, int N, int K)
{
  __shared__ __align__(16) bf16 As[2][128][64];
  __shared__ __align__(16) bf16 Bs[2][128][64];
  const int tid  = threadIdx.x;
  const int lane = tid & 63, wid = tid >> 6;
  const int l15  = lane & 15, lg = lane >> 4;
  const int L  = (blockIdx.x & 7) * 64 + (blockIdx.x >> 3);
  const int m0 = (L >> 3) * 128, n0 = (L & 7) * 128;
  const int wm = wid >> 1, wn = wid & 1;
  const char* Ab = (const char*)A;
  const char* Wb = (const char*)W;

  f32x4 acc[4][4] = {};

  GSTAGE(0, 0);
  asm volatile("s_waitcnt vmcnt(0)" ::: "memory");
  __syncthreads();

  int cur = 0;
  const int NT = K >> 6;
  for (int t = 0; t < NT; ++t) {
    if (t + 1 < NT) GSTAGE((t + 1) << 6, cur ^ 1);

    bf16x8 af[4][2], bfr[4][2];
    #pragma unroll
    for (int i = 0; i < 4; ++i) {
      const int ra = wm * 64 + i * 16 + l15;
      const int rb = wn * 64 + i * 16 + l15;
      #pragma unroll
      for (int s = 0; s < 2; ++s) {
        const int co = (s * 64 + lg * 16);
        af[i][s]  = *reinterpret_cast<const bf16x8*>(
            (const char*)&As[cur][0][0] + ra * 128 + (co ^ ((ra & 7) << 4)));
        bfr[i][s] = *reinterpret_cast<const bf16x8*>(
            (const char*)&Bs[cur][0][0] + rb * 128 + (co ^ ((rb & 7) << 4)));
      }
    }
    __builtin_amdgcn_s_setprio(1);
    #pragma unroll
    for (int s = 0; s < 2; ++s)
      #pragma unroll
      for (int mi = 0; mi < 4; ++mi)
        #pragma unroll
        for (int ni = 0; ni < 4; ++ni)
          acc[mi][ni] = __builtin_amdgcn_mfma_f32_16x16x32_bf16(af[mi][s], bfr[ni][s], acc[mi][ni], 0, 0, 0);
    __builtin_amdgcn_s_setprio(0);

    asm volatile("s_waitcnt vmcnt(0)" ::: "memory");
    __syncthreads();
    cur ^= 1;
  }

  // epilogue: C row = lg*4 + reg, col = l15 within each 16x16 fragment
  #pragma unroll
  for (int ni = 0; ni < 4; ++ni) {
    const int col = n0 + wn * 64 + ni * 16 + l15;
    const float bi = bias[col];
    #pragma unroll
    for (int mi = 0; mi < 4; ++mi) {
      const int row0 = m0 + wm * 64 + mi * 16 + lg * 4;
      if (MODE == 0) {
        bf16* out = (bf16*)Cout;
        #pragma unroll
        for (int r = 0; r < 4; ++r)
          out[(size_t)(row0 + r) * N + col] = (bf16)(acc[mi][ni][r] + bi);
      } else if (MODE == 1) {
        bf16* out = (bf16*)Cout;
        bf16x4 vv;
        #pragma unroll
        for (int r = 0; r < 4; ++r) vv[r] = (bf16)(acc[mi][ni][r] + bi);
        const int seq = row0 & (S_LEN - 1);
        const int t6  = seq & 63;
        const int p0  = (seq & ~63) + ((t6 >> 5) << 5) + (((t6 >> 2) & 3) << 3)
                      + (((t6 >> 4) & 1) << 2);
        *reinterpret_cast<bf16x4*>(
            &out[((size_t)(row0 >> 11) * DIM + col) * S_LEN + p0]) = vv;
      } else if (MODE == 3) {
        bf16* out = (bf16*)Cout;
        #pragma unroll
        for (int r = 0; r < 4; ++r)
          out[(size_t)(row0 + r) * N + col] = (bf16)((acc[mi][ni][r] + bi) * QSCALE);
      } else {
        float* out = (float*)Cout;
        #pragma unroll
        for (int r = 0; r < 4; ++r)
          out[(size_t)(row0 + r) * N + col] = acc[mi][ni][r] + bi;
      }
    }
  }
}

// ---------------------------------------------------------------------------
// Flash attention, static-max softmax, prescaled Q, P in registers.
// This round: ALL per-tile addresses hoisted (LDS reads reduce to
// base + (t&1)*8192 + lane-const offset + nf*2048-immediate, since
// row&7 == l15&7; STAGE uses running global pointers), and the mask is
// applied as a packed AND on the cvt_pk output (bias-add into exp2 deleted).
// ---------------------------------------------------------------------------
__global__ __launch_bounds__(512, 4)
void attn_fwd(const bf16* __restrict__ Qb, const bf16* __restrict__ Kb,
              const bf16* __restrict__ Vt, const u64* __restrict__ mbits,
              bf16* __restrict__ ctx)
{
  __shared__ __align__(16) bf16 Kbuf[2][64][64];
  __shared__ __align__(16) bf16 Vbuf[2][64][64];

  const int tid  = threadIdx.x;
  const int lane = tid & 63;
  const int l15  = lane & 15, lg = lane >> 4;
  const int L  = (blockIdx.x & 7) * 64 + (blockIdx.x >> 3);
  const int qi = L & 7;
  const int hb = L >> 3;
  const int h  = hb & 15, b = hb >> 4;
  const int w  = tid >> 6;
  const int qbase = qi * 256 + w * 32;

  // --- hoisted staging addresses (running pointers) ---
  const int rr_s = tid >> 3;
  const int cG_s = ((tid & 7) << 4) ^ ((rr_s & 7) << 4);
  const char* gk = (const char*)Kb + ((size_t)(b * S_LEN + rr_s) * DIM + h * DK) * 2 + cG_s;
  const char* gv = (const char*)Vt + ((size_t)b * DIM + h * DK + rr_s) * (S_LEN * 2) + cG_s;
  char* lK = (char*)&Kbuf[0][0][0] + tid * 16;
  char* lV = (char*)&Vbuf[0][0][0] + tid * 16;

  // --- hoisted LDS read offsets (lane-constant; row&7 == l15&7) ---
  const unsigned xo  = (l15 & 7) << 4;
  const unsigned ko0 = l15 * 128 + ((lg * 16) ^ xo);
  const unsigned ko1 = l15 * 128 + (((64 + lg * 16)) ^ xo);
  const char* KB = (const char*)&Kbuf[0][0][0];
  const char* VB = (const char*)&Vbuf[0][0][0];

  // Q fragments (B-operand), rows q = qbase + qg*16 + l15  (Q prescaled)
  bf16x8 qf[2][2];
  #pragma unroll
  for (int qg = 0; qg < 2; ++qg) {
    const size_t qrow = (size_t)b * S_LEN + qbase + qg * 16 + l15;
    #pragma unroll
    for (int s = 0; s < 2; ++s)
      qf[qg][s] = *reinterpret_cast<const bf16x8*>(&Qb[qrow * DIM + h * DK + s * 32 + lg * 8]);
  }

  bf16x8 onesf;
  #pragma unroll
  for (int j = 0; j < 8; ++j) onesf[j] = (bf16)1.0f;

  union pqu { unsigned u[8]; bf16x8 frag[2]; };

  f32x4 o[2][4] = {};
  f32x4 o_l[2] = {};
  const u64* mp0 = mbits + ((size_t)b * S_LEN + qbase + l15) * (S_LEN / 64);
  const u64* mp1 = mp0 + (size_t)16 * (S_LEN / 64);

  // prologue: stage tile 0, load mask 0
  gload16(gk, lK);  gload16(gv, lV);
  gk += 64 * DIM * 2;  gv += 64 * 2;
  u64 mbc[2] = { mp0[0], mp1[0] };
  mp0++; mp1++;

  const int NT = S_LEN / 64;   // 32
  for (int t = 0; t < NT; ++t) {
    asm volatile("s_waitcnt vmcnt(0)" ::: "memory");   // tile t landed
    __syncthreads();

    u64 mbn[2] = {0, 0};
    if (t + 1 < NT) {
      mbn[0] = *mp0++;
      mbn[1] = *mp1++;
      const unsigned nb = ((t + 1) & 1) << 13;
      gload16(gk, lK + nb);
      gload16(gv, lV + nb);
      gk += 64 * DIM * 2;
      gv += 64 * 2;
    }

    const unsigned tb = (t & 1) << 13;

    // --- QK^T: sc[qg][nf][r] = S[k = kt+nf*16+lg*4+r][q = qbase+qg*16+l15]
    f32x4 sc[2][4] = {};
    __builtin_amdgcn_s_setprio(1);
    #pragma unroll
    for (int s = 0; s < 2; ++s) {
      const char* kp = KB + tb + (s ? ko1 : ko0);
      #pragma unroll
      for (int nf = 0; nf < 4; ++nf) {
        bf16x8 kf = *reinterpret_cast<const bf16x8*>(kp + nf * 2048);
        sc[0][nf] = __builtin_amdgcn_mfma_f32_16x16x32_bf16(kf, qf[0][s], sc[0][nf], 0, 0, 0);
        sc[1][nf] = __builtin_amdgcn_mfma_f32_16x16x32_bf16(kf, qf[1][s], sc[1][nf], 0, 0, 0);
      }
    }
    __builtin_amdgcn_s_setprio(0);

    // --- softmax: p = exp2(sc); mask applied as packed AND after cvt_pk
    pqu W[2];
    #pragma unroll
    for (int qg = 0; qg < 2; ++qg) {
      #pragma unroll
      for (int nf = 0; nf < 4; ++nf) {
        const unsigned mm = (unsigned)(mbc[qg] >> (nf * 16 + lg * 4));  // bits 0..3
        float e0 = exp2fast(sc[qg][nf][0]);
        float e1 = exp2fast(sc[qg][nf][1]);
        float e2 = exp2fast(sc[qg][nf][2]);
        float e3 = exp2fast(sc[qg][nf][3]);
        const unsigned m01 = ((unsigned)(((int)(mm << 31)) >> 31) & 0x0000FFFFu)
                           | ((unsigned)(((int)(mm << 30)) >> 31) & 0xFFFF0000u);
        const unsigned m23 = ((unsigned)(((int)(mm << 29)) >> 31) & 0x0000FFFFu)
                           | ((unsigned)(((int)(mm << 28)) >> 31) & 0xFFFF0000u);
        W[qg].u[nf * 2 + 0] = cvt_pk_bf16(e0, e1) & m01;
        W[qg].u[nf * 2 + 1] = cvt_pk_bf16(e2, e3) & m23;
      }
    }

    // --- PV: A = P from registers (k-order pi), B = permuted V tile
    __builtin_amdgcn_s_setprio(1);
    #pragma unroll
    for (int s = 0; s < 2; ++s) {
      const char* vp = VB + tb + (s ? ko1 : ko0);
      #pragma unroll
      for (int nf = 0; nf < 4; ++nf) {
        bf16x8 vf = *reinterpret_cast<const bf16x8*>(vp + nf * 2048);
        o[0][nf] = __builtin_amdgcn_mfma_f32_16x16x32_bf16(W[0].frag[s], vf, o[0][nf], 0, 0, 0);
        o[1][nf] = __builtin_amdgcn_mfma_f32_16x16x32_bf16(W[1].frag[s], vf, o[1][nf], 0, 0, 0);
      }
      o_l[0] = __builtin_amdgcn_mfma_f32_16x16x32_bf16(W[0].frag[s], onesf, o_l[0], 0, 0, 0);
      o_l[1] = __builtin_amdgcn_mfma_f32_16x16x32_bf16(W[1].frag[s], onesf, o_l[1], 0, 0, 0);
    }
    __builtin_amdgcn_s_setprio(0);

    mbc[0] = mbn[0]; mbc[1] = mbn[1];
  }

  // --- epilogue: o_l[qg][r] is l[q] in o's row layout -> no shuffles
  #pragma unroll
  for (int qg = 0; qg < 2; ++qg) {
    float lf[4];
    #pragma unroll
    for (int r = 0; r < 4; ++r) lf[r] = 1.0f / o_l[qg][r];
    #pragma unroll
    for (int nf = 0; nf < 4; ++nf)
      #pragma unroll
      for (int r = 0; r < 4; ++r) {
        const int q = qbase + qg * 16 + lg * 4 + r;
        ctx[((size_t)b * S_LEN + q) * DIM + h * DK + nf * 16 + l15] = (bf16)(o[qg][nf][r] * lf[r]);
      }
  }
}

// ---------------------------------------------------------------------------
extern "C" void kernel_launch(void* const* d_in, const int* in_sizes, int n_in,
                              void* d_out, int out_size, void* d_ws, size_t ws_size,
                              hipStream_t stream)
{
  const float* q    = (const float*)d_in[0];
  const float* k    = (const float*)d_in[1];
  const float* v    = (const float*)d_in[2];
  const int*   mask = (const int*)  d_in[3];
  const float* Wq   = (const float*)d_in[4];
  const float* bq   = (const float*)d_in[5];
  const float* Wk   = (const float*)d_in[6];
  const float* bk   = (const float*)d_in[7];
  const float* Wv   = (const float*)d_in[8];
  const float* bv   = (const float*)d_in[9];
  const float* Wo   = (const float*)d_in[10];
  const float* bo   = (const float*)d_in[11];
  float* out = (float*)d_out;

  const size_t NE = (size_t)BATCH * S_LEN * DIM;  // 8.39M elements
  const size_t NW = (size_t)DIM * DIM;            // 1.05M elements
  bf16* qB  = (bf16*)d_ws;                        // bf16 copies of inputs
  bf16* kB  = qB + NE;
  bf16* vB  = kB + NE;
  bf16* Qb  = vB + NE;                            // projected Q,K,V
  bf16* Kb  = Qb + NE;
  bf16* Vt  = Kb + NE;
  bf16* WqB = Vt + NE;                            // bf16 weights
  bf16* WkB = WqB + NW;
  bf16* WvB = WkB + NW;
  bf16* WoB = WvB + NW;
  u64*  bits = (u64*)(WoB + NW);                  // 2 MB
  bf16* ctx = qB;                                 // reuse: qB dead after GEMM1

  const int M = BATCH * S_LEN;  // 8192

  pack_mask<<<(BATCH * S_LEN * (S_LEN / 64)) / 4, 256, 0, stream>>>(mask, bits);
  conv_bf16<<<dim3(NE / 2048, 3), 256, 0, stream>>>(q, k, v, v, qB, kB, vB, vB);
  conv_bf16<<<dim3(NW / 2048, 4), 256, 0, stream>>>(Wq, Wk, Wv, Wo, WqB, WkB, WvB, WoB);

  gemm_bt<3><<<512, 256, 0, stream>>>(qB, WqB, bq, Qb, M, DIM, DIM);   // Q prescaled
  gemm_bt<0><<<512, 256, 0, stream>>>(kB, WkB, bk, Kb, M, DIM, DIM);
  gemm_bt<1><<<512, 256, 0, stream>>>(vB, WvB, bv, Vt, M, DIM, DIM);   // V k-permuted

  attn_fwd<<<512, 512, 0, stream>>>(Qb, Kb, Vt, bits, ctx);

  gemm_bt<2><<<512, 256, 0, stream>>>(ctx, WoB, bo, out, M, DIM, DIM);
}